// Round 7
// baseline (280.274 us; speedup 1.0000x reference)
//
#include <hip/hip_runtime.h>
#include <hip/hip_bf16.h>
#include <math.h>

#define N_TOK 16384
#define DIM   2048
#define NE    64
#define TOPK  9

#define ROWS     32            // rows per block
#define KC       32            // k per pipeline step
#define NSTEP    (DIM / KC)    // 64
#define NTHREADS 256           // 4 waves

typedef short  short8  __attribute__((ext_vector_type(8)));
typedef float  float4_ __attribute__((ext_vector_type(4)));
typedef unsigned short ushort_t;

__device__ __forceinline__ unsigned pk2(float a, float b) {
    float2 f; f.x = a; f.y = b;
    __hip_bfloat162 h = __float22bfloat162_rn(f);   // low16 = bf16(a)
    unsigned u;
    __builtin_memcpy(&u, &h, 4);
    return u;
}

// 8 fp32 -> bf16 hi frag + bf16 lo frag (2-term split)
__device__ __forceinline__ void cvt8(const float4_ va, const float4_ vb,
                                     short8* h, short8* l) {
    union { short8 s; unsigned u[4]; } H, L;
    const float f[8] = {va[0], va[1], va[2], va[3], vb[0], vb[1], vb[2], vb[3]};
#pragma unroll
    for (int i = 0; i < 4; ++i) {
        const float a = f[2 * i], b = f[2 * i + 1];
        const unsigned p = pk2(a, b);
        H.u[i] = p;
        const float ha = __uint_as_float(p << 16);
        const float hb = __uint_as_float(p & 0xffff0000u);
        L.u[i] = pk2(a - ha, b - hb);
    }
    *h = H.s; *l = L.s;
}

__device__ __forceinline__ float wave_max64(float v) {
#pragma unroll
    for (int off = 32; off > 0; off >>= 1)
        v = fmaxf(v, __shfl_xor(v, off, 64));
    return v;
}
__device__ __forceinline__ float wave_sum64(float v) {
#pragma unroll
    for (int off = 32; off > 0; off >>= 1)
        v += __shfl_xor(v, off, 64);
    return v;
}

// ---- prep: Wr|Wn (fp32, D x 64 each) -> B-fragment-ordered bf16 hi/lo ----
// pair p=(kcg*8+ct) occupies 2 KB: hi slot at p*2048B, lo at +1024B
// elem l*8+j = B[k=kcg*32+(l>>4)*8+j][n=ct*16+(l&15)]
// Also zeroes the importance/load accumulator region of out (block 0).
__global__ __launch_bounds__(256)
void prep_w(const float* __restrict__ Wr, const float* __restrict__ Wn,
            ushort_t* __restrict__ wsW, float* __restrict__ out)
{
    if (blockIdx.x == 0 && threadIdx.x < 2 * NE)
        (out + (size_t)2 * N_TOK * NE)[threadIdx.x] = 0.f;
    const int gid = blockIdx.x * 256 + threadIdx.x;   // [0, 64*8*64)
    const int l   = gid & 63;
    const int ct  = (gid >> 6) & 7;
    const int kcg = gid >> 9;                         // 0..63
    const int n   = ct * 16 + (l & 15);
    const int k0  = kcg * 32 + (l >> 4) * 8;
    const float* src = (n < NE) ? (Wr + n) : (Wn + (n - NE));
    union { short8 s; ushort_t us[8]; } H, L;
#pragma unroll
    for (int j = 0; j < 8; ++j) {
        const float v = src[(size_t)(k0 + j) * NE];
        const unsigned uv = __float_as_uint(v);
        const unsigned hb = (uv + 0x7fffu + ((uv >> 16) & 1u)) & 0xffff0000u;
        const float lo = v - __uint_as_float(hb);
        const unsigned ul = __float_as_uint(lo);
        H.us[j] = (ushort_t)(hb >> 16);
        L.us[j] = (ushort_t)((ul + 0x7fffu + ((ul >> 16) & 1u)) >> 16);
    }
    const size_t p = (size_t)(kcg * 8 + ct);
    *(short8*)(wsW + p * 1024 + l * 8)        = H.s;   // hi  (BUGFIX: + l*8)
    *(short8*)(wsW + p * 1024 + 512 + l * 8)  = L.s;   // lo
}

__global__ __launch_bounds__(NTHREADS, 2)
void moe_main(const float* __restrict__ x,
              const float* __restrict__ br,
              const float* __restrict__ bn,
              const float* __restrict__ noise_eps,
              const float* __restrict__ gumbel,
              const ushort_t* __restrict__ wsW,
              float* __restrict__ out)
{
    __shared__ float smem[4160];      // epilogue only: 2 x (32 x 65)

    const int t    = threadIdx.x;
    const int lane = t & 63;
    const int w    = t >> 6;          // wave 0..3, owns col-tiles {2w, 2w+1}
    const int c4   = lane & 15;
    const int q    = lane >> 4;
    const int row0 = blockIdx.x * ROWS;

    // A direct-from-global: lane (c4,q) reads x[row0 + rt*16 + c4][s*32 + q*8 .. +7]
    const float* x0 = x + (size_t)(row0 + c4)      * DIM + q * 8;
    const float* x1 = x + (size_t)(row0 + 16 + c4) * DIM + q * 8;
    // B from ws (L2-resident): step s -> pairs (s*8 + 2w + cc), hi at +0, lo at +1024
    const char* bbase = (const char*)wsW + (size_t)(2 * w) * 2048 + lane * 16;

    float4_ acc[2][2];
#pragma unroll
    for (int rt = 0; rt < 2; ++rt)
#pragma unroll
        for (int cc = 0; cc < 2; ++cc)
            acc[rt][cc] = (float4_)(0.f);

    // depth-2 software pipeline, all loads global->VGPR, NO barriers in K-loop
    float4_ pa[2][4];
    short8  pb[2][4];
#define LOAD_STEP(s_, buf_)  do {                                        \
        const float* a0 = x0 + (s_) * KC;                                \
        const float* a1 = x1 + (s_) * KC;                                \
        pa[buf_][0] = *(const float4_*)(a0);                             \
        pa[buf_][1] = *(const float4_*)(a0 + 4);                         \
        pa[buf_][2] = *(const float4_*)(a1);                             \
        pa[buf_][3] = *(const float4_*)(a1 + 4);                         \
        const char* B = bbase + (size_t)(s_) * 16384;                    \
        pb[buf_][0] = *(const short8*)(B);                               \
        pb[buf_][1] = *(const short8*)(B + 1024);                        \
        pb[buf_][2] = *(const short8*)(B + 2048);                        \
        pb[buf_][3] = *(const short8*)(B + 3072);                        \
    } while (0)
#define COMPUTE_STEP(buf_) do {                                                              \
        short8 ah, al;                                                                       \
        const short8 bh0 = pb[buf_][0], bl0 = pb[buf_][1];                                   \
        const short8 bh1 = pb[buf_][2], bl1 = pb[buf_][3];                                   \
        cvt8(pa[buf_][0], pa[buf_][1], &ah, &al);                                            \
        acc[0][0] = __builtin_amdgcn_mfma_f32_16x16x32_bf16(ah, bh0, acc[0][0], 0, 0, 0);    \
        acc[0][0] = __builtin_amdgcn_mfma_f32_16x16x32_bf16(al, bh0, acc[0][0], 0, 0, 0);    \
        acc[0][0] = __builtin_amdgcn_mfma_f32_16x16x32_bf16(ah, bl0, acc[0][0], 0, 0, 0);    \
        acc[0][1] = __builtin_amdgcn_mfma_f32_16x16x32_bf16(ah, bh1, acc[0][1], 0, 0, 0);    \
        acc[0][1] = __builtin_amdgcn_mfma_f32_16x16x32_bf16(al, bh1, acc[0][1], 0, 0, 0);    \
        acc[0][1] = __builtin_amdgcn_mfma_f32_16x16x32_bf16(ah, bl1, acc[0][1], 0, 0, 0);    \
        cvt8(pa[buf_][2], pa[buf_][3], &ah, &al);                                            \
        acc[1][0] = __builtin_amdgcn_mfma_f32_16x16x32_bf16(ah, bh0, acc[1][0], 0, 0, 0);    \
        acc[1][0] = __builtin_amdgcn_mfma_f32_16x16x32_bf16(al, bh0, acc[1][0], 0, 0, 0);    \
        acc[1][0] = __builtin_amdgcn_mfma_f32_16x16x32_bf16(ah, bl0, acc[1][0], 0, 0, 0);    \
        acc[1][1] = __builtin_amdgcn_mfma_f32_16x16x32_bf16(ah, bh1, acc[1][1], 0, 0, 0);    \
        acc[1][1] = __builtin_amdgcn_mfma_f32_16x16x32_bf16(al, bh1, acc[1][1], 0, 0, 0);    \
        acc[1][1] = __builtin_amdgcn_mfma_f32_16x16x32_bf16(ah, bl1, acc[1][1], 0, 0, 0);    \
    } while (0)

    LOAD_STEP(0, 0);
    LOAD_STEP(1, 1);
#pragma unroll 1
    for (int s = 0; s < NSTEP - 2; s += 2) {
        COMPUTE_STEP(0);
        LOAD_STEP(s + 2, 0);
        COMPUTE_STEP(1);
        LOAD_STEP(s + 3, 1);
    }
    COMPUTE_STEP(0);
    COMPUTE_STEP(1);

    // ---- epilogue: transpose C tiles through LDS, then per-row wave ops ----
    float* rawS = &smem[0];            // 32 x 65 (padded)
    float* noiS = &smem[2080];         // 32 x 65
#pragma unroll
    for (int rt = 0; rt < 2; ++rt)
#pragma unroll
        for (int cc = 0; cc < 2; ++cc) {
            const int colg = (2 * w + cc) * 16 + c4;   // 0..127; <64 raw else noise
            float* basep = (colg < NE) ? rawS : noiS;
            const int col = colg & 63;
#pragma unroll
            for (int v = 0; v < 4; ++v) {
                const int row = rt * 16 + q * 4 + v;   // C/D: col=lane&15, row=quad*4+reg
                basep[row * 65 + col] = acc[rt][cc][v];
            }
        }
    __syncthreads();

    const float br_l = br[lane];
    const float bn_l = bn[lane];
    float imp_acc = 0.f, load_acc = 0.f;
    float* out_em   = out;
    float* out_rp   = out + (size_t)N_TOK * NE;
    float* out_imp  = out + (size_t)2 * N_TOK * NE;
    float* out_load = out_imp + NE;

#pragma unroll 1
    for (int r = 0; r < 8; ++r) {
        const int lrow = w * 8 + r;
        const int row  = row0 + lrow;
        const float raw = rawS[lrow * 65 + lane] + br_l;
        const float nl  = noiS[lrow * 65 + lane] + bn_l;
        const float sd = fmaxf(nl, 0.f) + log1pf(expf(-fabsf(nl))) + 0.01f;
        const float epsv = noise_eps[(size_t)row * NE + lane];
        const float gum  = gumbel  [(size_t)row * NE + lane];
        const float noisy = fmaf(epsv, sd, raw);

        float cur = noisy;
        float thr = 0.f, m0 = 0.f;
#pragma unroll 1
        for (int k = 0; k < TOPK; ++k) {
            const float m = wave_max64(cur);
            if (k == 0) m0 = m;
            thr = m;
            const unsigned long long bm = __ballot(cur == m);
            const int first = __ffsll(bm) - 1;
            if (lane == first) cur = -INFINITY;
        }
        const float hard = (noisy >= thr) ? 1.f : 0.f;

        const float g  = noisy + gum;
        const float eg = expf(g - wave_max64(g));
        const float ms = eg / wave_sum64(eg);
        const float em = (hard - ms) + ms;

        const float en = expf(noisy - m0);
        const float rp = en / wave_sum64(en);

        const float er = expf(raw - wave_max64(raw));
        imp_acc += er / wave_sum64(er);

        const float z = (thr - raw) / sd;
        load_acc += 0.5f * erfcf(z * 45.254833995939045f);

        out_em[(size_t)row * NE + lane] = em;
        out_rp[(size_t)row * NE + lane] = rp;
    }

    __syncthreads();                   // rawS/noiS reads done; reuse for reduction
    smem[w * 64 + lane]       = imp_acc;
    smem[256 + w * 64 + lane] = load_acc;
    __syncthreads();
    if (w == 0) {
        const float s1 = smem[lane] + smem[64 + lane] + smem[128 + lane] + smem[192 + lane];
        const float s2 = smem[256 + lane] + smem[320 + lane] + smem[384 + lane] + smem[448 + lane];
        atomicAdd(&out_imp[lane], s1);
        atomicAdd(&out_load[lane], s2);
    }
}

extern "C" void kernel_launch(void* const* d_in, const int* in_sizes, int n_in,
                              void* d_out, int out_size, void* d_ws, size_t ws_size,
                              hipStream_t stream)
{
    const float* x         = (const float*)d_in[0];
    const float* Wr        = (const float*)d_in[1];
    const float* br        = (const float*)d_in[2];
    const float* Wn        = (const float*)d_in[3];
    const float* bn        = (const float*)d_in[4];
    const float* noise_eps = (const float*)d_in[5];
    const float* gumbel    = (const float*)d_in[6];
    float* out = (float*)d_out;
    ushort_t* wsW = (ushort_t*)d_ws;   // 1 MB (512 pairs x 2 KB)

    prep_w<<<128, 256, 0, stream>>>(Wr, Wn, wsW, out);
    moe_main<<<N_TOK / ROWS, NTHREADS, 0, stream>>>(
        x, br, bn, noise_eps, gumbel, wsW, out);
}

// Round 8
// 280.245 us; speedup vs baseline: 1.0001x; 1.0001x over previous
//
#include <hip/hip_runtime.h>
#include <hip/hip_bf16.h>
#include <math.h>

#define N_TOK 16384
#define DIM   2048
#define NE    64
#define TOPK  9

#define ROWS     32            // rows per block
#define KC       32            // k per pipeline step
#define NSTEP    (DIM / KC)    // 64
#define NTHREADS 256           // 4 waves
#define DEPTH    4             // software-pipeline depth (step buffers)

typedef short  short8  __attribute__((ext_vector_type(8)));
typedef float  float4_ __attribute__((ext_vector_type(4)));
typedef unsigned short ushort_t;

__device__ __forceinline__ unsigned pk2(float a, float b) {
    float2 f; f.x = a; f.y = b;
    __hip_bfloat162 h = __float22bfloat162_rn(f);   // low16 = bf16(a)
    unsigned u;
    __builtin_memcpy(&u, &h, 4);
    return u;
}

// 8 fp32 -> bf16 hi frag + bf16 lo frag (2-term split)
__device__ __forceinline__ void cvt8(const float4_ va, const float4_ vb,
                                     short8* h, short8* l) {
    union { short8 s; unsigned u[4]; } H, L;
    const float f[8] = {va[0], va[1], va[2], va[3], vb[0], vb[1], vb[2], vb[3]};
#pragma unroll
    for (int i = 0; i < 4; ++i) {
        const float a = f[2 * i], b = f[2 * i + 1];
        const unsigned p = pk2(a, b);
        H.u[i] = p;
        const float ha = __uint_as_float(p << 16);
        const float hb = __uint_as_float(p & 0xffff0000u);
        L.u[i] = pk2(a - ha, b - hb);
    }
    *h = H.s; *l = L.s;
}

__device__ __forceinline__ float wave_max64(float v) {
#pragma unroll
    for (int off = 32; off > 0; off >>= 1)
        v = fmaxf(v, __shfl_xor(v, off, 64));
    return v;
}
__device__ __forceinline__ float wave_sum64(float v) {
#pragma unroll
    for (int off = 32; off > 0; off >>= 1)
        v += __shfl_xor(v, off, 64);
    return v;
}

// ---- prep: Wr|Wn (fp32, D x 64 each) -> B-fragment-ordered bf16 hi/lo ----
// pair p=(kcg*8+ct) occupies 2 KB: hi slot at p*2048B, lo at +1024B
// elem l*8+j = B[k=kcg*32+(l>>4)*8+j][n=ct*16+(l&15)]
// Also zeroes the importance/load accumulator region of out (block 0).
__global__ __launch_bounds__(256)
void prep_w(const float* __restrict__ Wr, const float* __restrict__ Wn,
            ushort_t* __restrict__ wsW, float* __restrict__ out)
{
    if (blockIdx.x == 0 && threadIdx.x < 2 * NE)
        (out + (size_t)2 * N_TOK * NE)[threadIdx.x] = 0.f;
    const int gid = blockIdx.x * 256 + threadIdx.x;   // [0, 64*8*64)
    const int l   = gid & 63;
    const int ct  = (gid >> 6) & 7;
    const int kcg = gid >> 9;                         // 0..63
    const int n   = ct * 16 + (l & 15);
    const int k0  = kcg * 32 + (l >> 4) * 8;
    const float* src = (n < NE) ? (Wr + n) : (Wn + (n - NE));
    union { short8 s; ushort_t us[8]; } H, L;
#pragma unroll
    for (int j = 0; j < 8; ++j) {
        const float v = src[(size_t)(k0 + j) * NE];
        const unsigned uv = __float_as_uint(v);
        const unsigned hb = (uv + 0x7fffu + ((uv >> 16) & 1u)) & 0xffff0000u;
        const float lo = v - __uint_as_float(hb);
        const unsigned ul = __float_as_uint(lo);
        H.us[j] = (ushort_t)(hb >> 16);
        L.us[j] = (ushort_t)((ul + 0x7fffu + ((ul >> 16) & 1u)) >> 16);
    }
    const size_t p = (size_t)(kcg * 8 + ct);
    *(short8*)(wsW + p * 1024 + l * 8)        = H.s;   // hi
    *(short8*)(wsW + p * 1024 + 512 + l * 8)  = L.s;   // lo
}

__global__ __launch_bounds__(NTHREADS, 2)
void moe_main(const float* __restrict__ x,
              const float* __restrict__ br,
              const float* __restrict__ bn,
              const float* __restrict__ noise_eps,
              const float* __restrict__ gumbel,
              const ushort_t* __restrict__ wsW,
              float* __restrict__ out)
{
    __shared__ float smem[4160];      // epilogue only: 2 x (32 x 65)

    const int t    = threadIdx.x;
    const int lane = t & 63;
    const int w    = t >> 6;          // wave 0..3, owns col-tiles {2w, 2w+1}
    const int c4   = lane & 15;
    const int q    = lane >> 4;
    const int row0 = blockIdx.x * ROWS;

    // A direct-from-global: lane (c4,q) reads x[row0 + rt*16 + c4][s*32 + q*8 .. +7]
    const float* x0 = x + (size_t)(row0 + c4)      * DIM + q * 8;
    const float* x1 = x + (size_t)(row0 + 16 + c4) * DIM + q * 8;
    // B from ws (L2-resident): step s -> pairs (s*8 + 2w + cc), hi at +0, lo at +1024
    const char* bbase = (const char*)wsW + (size_t)(2 * w) * 2048 + lane * 16;

    float4_ acc[2][2];
#pragma unroll
    for (int rt = 0; rt < 2; ++rt)
#pragma unroll
        for (int cc = 0; cc < 2; ++cc)
            acc[rt][cc] = (float4_)(0.f);

    // depth-4 software pipeline, all loads global->VGPR, NO barriers in K-loop
    float4_ pa[DEPTH][4];
    short8  pb[DEPTH][4];
#define LOAD_STEP(s_, buf_)  do {                                        \
        const float* a0 = x0 + (s_) * KC;                                \
        const float* a1 = x1 + (s_) * KC;                                \
        pa[buf_][0] = *(const float4_*)(a0);                             \
        pa[buf_][1] = *(const float4_*)(a0 + 4);                         \
        pa[buf_][2] = *(const float4_*)(a1);                             \
        pa[buf_][3] = *(const float4_*)(a1 + 4);                         \
        const char* B = bbase + (size_t)(s_) * 16384;                    \
        pb[buf_][0] = *(const short8*)(B);                               \
        pb[buf_][1] = *(const short8*)(B + 1024);                        \
        pb[buf_][2] = *(const short8*)(B + 2048);                        \
        pb[buf_][3] = *(const short8*)(B + 3072);                        \
    } while (0)
#define COMPUTE_STEP(buf_) do {                                                              \
        short8 ah, al;                                                                       \
        const short8 bh0 = pb[buf_][0], bl0 = pb[buf_][1];                                   \
        const short8 bh1 = pb[buf_][2], bl1 = pb[buf_][3];                                   \
        cvt8(pa[buf_][0], pa[buf_][1], &ah, &al);                                            \
        acc[0][0] = __builtin_amdgcn_mfma_f32_16x16x32_bf16(ah, bh0, acc[0][0], 0, 0, 0);    \
        acc[0][0] = __builtin_amdgcn_mfma_f32_16x16x32_bf16(al, bh0, acc[0][0], 0, 0, 0);    \
        acc[0][0] = __builtin_amdgcn_mfma_f32_16x16x32_bf16(ah, bl0, acc[0][0], 0, 0, 0);    \
        acc[0][1] = __builtin_amdgcn_mfma_f32_16x16x32_bf16(ah, bh1, acc[0][1], 0, 0, 0);    \
        acc[0][1] = __builtin_amdgcn_mfma_f32_16x16x32_bf16(al, bh1, acc[0][1], 0, 0, 0);    \
        acc[0][1] = __builtin_amdgcn_mfma_f32_16x16x32_bf16(ah, bl1, acc[0][1], 0, 0, 0);    \
        cvt8(pa[buf_][2], pa[buf_][3], &ah, &al);                                            \
        acc[1][0] = __builtin_amdgcn_mfma_f32_16x16x32_bf16(ah, bh0, acc[1][0], 0, 0, 0);    \
        acc[1][0] = __builtin_amdgcn_mfma_f32_16x16x32_bf16(al, bh0, acc[1][0], 0, 0, 0);    \
        acc[1][0] = __builtin_amdgcn_mfma_f32_16x16x32_bf16(ah, bl0, acc[1][0], 0, 0, 0);    \
        acc[1][1] = __builtin_amdgcn_mfma_f32_16x16x32_bf16(ah, bh1, acc[1][1], 0, 0, 0);    \
        acc[1][1] = __builtin_amdgcn_mfma_f32_16x16x32_bf16(al, bh1, acc[1][1], 0, 0, 0);    \
        acc[1][1] = __builtin_amdgcn_mfma_f32_16x16x32_bf16(ah, bl1, acc[1][1], 0, 0, 0);    \
    } while (0)

    LOAD_STEP(0, 0);
    LOAD_STEP(1, 1);
    LOAD_STEP(2, 2);
    LOAD_STEP(3, 3);
#pragma unroll 1
    for (int s = 0; s < NSTEP - 4; s += 4) {
        COMPUTE_STEP(0);
        LOAD_STEP(s + 4, 0);
        COMPUTE_STEP(1);
        LOAD_STEP(s + 5, 1);
        COMPUTE_STEP(2);
        LOAD_STEP(s + 6, 2);
        COMPUTE_STEP(3);
        LOAD_STEP(s + 7, 3);
    }
    COMPUTE_STEP(0);
    COMPUTE_STEP(1);
    COMPUTE_STEP(2);
    COMPUTE_STEP(3);

    // ---- epilogue: transpose C tiles through LDS, then per-row wave ops ----
    float* rawS = &smem[0];            // 32 x 65 (padded)
    float* noiS = &smem[2080];         // 32 x 65
#pragma unroll
    for (int rt = 0; rt < 2; ++rt)
#pragma unroll
        for (int cc = 0; cc < 2; ++cc) {
            const int colg = (2 * w + cc) * 16 + c4;   // 0..127; <64 raw else noise
            float* basep = (colg < NE) ? rawS : noiS;
            const int col = colg & 63;
#pragma unroll
            for (int v = 0; v < 4; ++v) {
                const int row = rt * 16 + q * 4 + v;   // C/D: col=lane&15, row=quad*4+reg
                basep[row * 65 + col] = acc[rt][cc][v];
            }
        }
    __syncthreads();

    const float br_l = br[lane];
    const float bn_l = bn[lane];
    float imp_acc = 0.f, load_acc = 0.f;
    float* out_em   = out;
    float* out_rp   = out + (size_t)N_TOK * NE;
    float* out_imp  = out + (size_t)2 * N_TOK * NE;
    float* out_load = out_imp + NE;

#pragma unroll 1
    for (int r = 0; r < 8; ++r) {
        const int lrow = w * 8 + r;
        const int row  = row0 + lrow;
        const float raw = rawS[lrow * 65 + lane] + br_l;
        const float nl  = noiS[lrow * 65 + lane] + bn_l;
        const float sd = fmaxf(nl, 0.f) + log1pf(expf(-fabsf(nl))) + 0.01f;
        const float epsv = noise_eps[(size_t)row * NE + lane];
        const float gum  = gumbel  [(size_t)row * NE + lane];
        const float noisy = fmaf(epsv, sd, raw);

        float cur = noisy;
        float thr = 0.f, m0 = 0.f;
#pragma unroll 1
        for (int k = 0; k < TOPK; ++k) {
            const float m = wave_max64(cur);
            if (k == 0) m0 = m;
            thr = m;
            const unsigned long long bm = __ballot(cur == m);
            const int first = __ffsll(bm) - 1;
            if (lane == first) cur = -INFINITY;
        }
        const float hard = (noisy >= thr) ? 1.f : 0.f;

        const float g  = noisy + gum;
        const float eg = expf(g - wave_max64(g));
        const float ms = eg / wave_sum64(eg);
        const float em = (hard - ms) + ms;

        const float en = expf(noisy - m0);
        const float rp = en / wave_sum64(en);

        const float er = expf(raw - wave_max64(raw));
        imp_acc += er / wave_sum64(er);

        const float z = (thr - raw) / sd;
        load_acc += 0.5f * erfcf(z * 45.254833995939045f);

        out_em[(size_t)row * NE + lane] = em;
        out_rp[(size_t)row * NE + lane] = rp;
    }

    __syncthreads();                   // rawS/noiS reads done; reuse for reduction
    smem[w * 64 + lane]       = imp_acc;
    smem[256 + w * 64 + lane] = load_acc;
    __syncthreads();
    if (w == 0) {
        const float s1 = smem[lane] + smem[64 + lane] + smem[128 + lane] + smem[192 + lane];
        const float s2 = smem[256 + lane] + smem[320 + lane] + smem[384 + lane] + smem[448 + lane];
        atomicAdd(&out_imp[lane], s1);
        atomicAdd(&out_load[lane], s2);
    }
}

extern "C" void kernel_launch(void* const* d_in, const int* in_sizes, int n_in,
                              void* d_out, int out_size, void* d_ws, size_t ws_size,
                              hipStream_t stream)
{
    const float* x         = (const float*)d_in[0];
    const float* Wr        = (const float*)d_in[1];
    const float* br        = (const float*)d_in[2];
    const float* Wn        = (const float*)d_in[3];
    const float* bn        = (const float*)d_in[4];
    const float* noise_eps = (const float*)d_in[5];
    const float* gumbel    = (const float*)d_in[6];
    float* out = (float*)d_out;
    ushort_t* wsW = (ushort_t*)d_ws;   // 1 MB (512 pairs x 2 KB)

    prep_w<<<128, 256, 0, stream>>>(Wr, Wn, wsW, out);
    moe_main<<<N_TOK / ROWS, NTHREADS, 0, stream>>>(
        x, br, bn, noise_eps, gumbel, wsW, out);
}